// Round 6
// baseline (108.591 us; speedup 1.0000x reference)
//
#include <hip/hip_runtime.h>
#include <hip/hip_bf16.h>

#define N_NODES 20000
#define N_EDGES 100000
#define IN_DIM  128
#define HID     64
#define LAT     32
#define EDIM    16
#define EG      2     // edge-groups (of 16 edges) per block: 32 edges/block
                      // 100000 = 3125 * 32 exactly -> no tail anywhere

typedef __attribute__((ext_vector_type(8))) short bf16x8;
typedef __attribute__((ext_vector_type(4))) float f32x4;

__device__ __forceinline__ short f2bs(float f) {
    __hip_bfloat16 b = __float2bfloat16(f);
    short s;
    __builtin_memcpy(&s, &b, 2);
    return s;
}

// ---------------------------------------------------------------------------
// Fused prep: build all bf16 transposed weight tables in ws.
//   kwT  [4096][16] : kwT[c][d]  = kw[d][c]          (65536)
//   kbb8 [4096][8]  : kb[c] replicated 8x            (32768)   (kwT+65536)
//   wT   [64][128]  : wT[o][d]   = lin_w[d][o]       (8192)
//   rootT[64][64]   : rootT[o][d]= root_w[d][o]      (4096)
//   mlvT [64][64]   : o<32 -> mu_w[k][o], else lv_w  (4096)
// ---------------------------------------------------------------------------
__global__ __launch_bounds__(256) void k_prep(
        const float* __restrict__ kw,     const float* __restrict__ kb,
        const float* __restrict__ lin_w,  const float* __restrict__ root_w,
        const float* __restrict__ mu_w,   const float* __restrict__ lv_w,
        __hip_bfloat16* __restrict__ kwT, __hip_bfloat16* __restrict__ kbb8,
        __hip_bfloat16* __restrict__ wT,  __hip_bfloat16* __restrict__ rootT,
        __hip_bfloat16* __restrict__ mlvT) {
    int i = blockIdx.x * 256 + threadIdx.x;
    if (i < 65536) {
        int c = i & 4095, d = i >> 12;
        kwT[c * EDIM + d] = __float2bfloat16(kw[d * (HID * HID) + c]);
    } else if (i < 65536 + 32768) {
        int j = i - 65536;
        kbb8[j] = __float2bfloat16(kb[j >> 3]);
    } else if (i < 65536 + 32768 + 8192) {
        int j = i - (65536 + 32768);
        int o = j >> 7, d = j & 127;
        wT[j] = __float2bfloat16(lin_w[d * HID + o]);
    } else if (i < 65536 + 32768 + 8192 + 4096) {
        int j = i - (65536 + 32768 + 8192);
        int o = j >> 6, d = j & 63;
        rootT[j] = __float2bfloat16(root_w[d * HID + o]);
    } else {
        int j = i - (65536 + 32768 + 8192 + 4096);
        int o2 = j >> 6, k = j & 63;
        mlvT[j] = __float2bfloat16(o2 < 32 ? mu_w[k * LAT + o2]
                                           : lv_w[k * LAT + (o2 - 32)]);
    }
}

// ---------------------------------------------------------------------------
// Kernel A (MFMA): h = relu(x @ lin_in_w + lin_in_b)
// ---------------------------------------------------------------------------
__global__ __launch_bounds__(256) void k_lin_mfma(
        const float* __restrict__ x, const __hip_bfloat16* __restrict__ wT,
        const float* __restrict__ lin_b, float* __restrict__ h) {
    const int n0   = blockIdx.x * 16;
    const int q    = threadIdx.x >> 6;
    const int lane = threadIdx.x & 63;
    const int col  = lane & 15, grp = lane >> 4;
    const int oo   = q * 16 + col;

    f32x4 acc = {0.f, 0.f, 0.f, 0.f};
    const float* xp = x + (size_t)(n0 + col) * IN_DIM + grp * 8;
    const __hip_bfloat16* bp = wT + (size_t)oo * IN_DIM + grp * 8;
#pragma unroll
    for (int it = 0; it < 4; ++it) {
        float4 xa = *(const float4*)(xp + it * 32);
        float4 xb = *(const float4*)(xp + it * 32 + 4);
        bf16x8 af;
        af[0] = f2bs(xa.x); af[1] = f2bs(xa.y); af[2] = f2bs(xa.z); af[3] = f2bs(xa.w);
        af[4] = f2bs(xb.x); af[5] = f2bs(xb.y); af[6] = f2bs(xb.z); af[7] = f2bs(xb.w);
        bf16x8 bfv = *(const bf16x8*)(bp + it * 32);
        acc = __builtin_amdgcn_mfma_f32_16x16x32_bf16(af, bfv, acc, 0, 0, 0);
    }
    const float bias = lin_b[oo];
#pragma unroll
    for (int j = 0; j < 4; ++j) {
        int row = grp * 4 + j;
        h[(size_t)(n0 + row) * HID + oo] = fmaxf(acc[j] + bias, 0.f);
    }
}

// ---------------------------------------------------------------------------
// Kernel B (MFMA): fused edge-MLP + message + scatter-add.
// Block = 32 edges (2 groups of 16), wave q = oo quarter. Per hh: ONE
// B-fragment load (kwT row / bias row; k-slot trick: k<16 = ea@kw, k=16 =
// bias via A=1.0), TWO MFMAs reusing it. Epilogue: packed relu+fma against
// s_hT broadcast. unroll 4 -> 4 B-loads in flight (L2-latency cover).
// No tail: 100000 edges = 3125 blocks * 32.
// ---------------------------------------------------------------------------
__global__ __launch_bounds__(256) void k_edge(
        const int* __restrict__ ei, const float* __restrict__ ea,
        const float* __restrict__ h, const __hip_bfloat16* __restrict__ kwT,
        float* __restrict__ num, float* __restrict__ cnt) {
    __shared__ float s_hT[HID][EG * 16 + 4];   // row stride 36 floats (144B)
    __shared__ int   s_dst[EG * 16];

    const int e0   = blockIdx.x * (EG * 16);
    const int tid  = threadIdx.x;
    const int q    = tid >> 6, lane = tid & 63;
    const int col  = lane & 15, grp = lane >> 4;

    // stage h[src]^T (32 edges x 64 hh); wave-coalesced global reads
    for (int i = tid; i < EG * 16 * HID; i += 256) {
        int r = i >> 6, c = i & 63;
        int src = ei[e0 + r];
        s_hT[c][r] = h[(size_t)src * HID + c];
    }
    if (tid < EG * 16) s_dst[tid] = ei[N_EDGES + e0 + tid];
    __syncthreads();

    // A fragments (loop-invariant), one per edge-group
    bf16x8 af[EG];
#pragma unroll
    for (int g = 0; g < EG; ++g) {
        bf16x8 a = {};
        if (grp < 2) {
            const float* ep = ea + (size_t)(e0 + g * 16 + col) * EDIM + grp * 8;
            float4 a0 = *(const float4*)ep;
            float4 a1 = *(const float4*)(ep + 4);
            a[0] = f2bs(a0.x); a[1] = f2bs(a0.y); a[2] = f2bs(a0.z); a[3] = f2bs(a0.w);
            a[4] = f2bs(a1.x); a[5] = f2bs(a1.y); a[6] = f2bs(a1.z); a[7] = f2bs(a1.w);
        } else if (grp == 2) {
            a[0] = (short)0x3F80;    // bf16(1.0) -> bias row k=16
        }
        af[g] = a;
    }

    int off, stride;
    if (grp < 2) { off = (q * 16 + col) * EDIM + grp * 8; stride = 1024; }
    else         { off = 65536 + (q * 16 + col) * 8;      stride = 512;  }

    f32x4 msg[EG];
#pragma unroll
    for (int g = 0; g < EG; ++g) msg[g] = (f32x4){0.f, 0.f, 0.f, 0.f};
    const f32x4 z4 = {0.f, 0.f, 0.f, 0.f};

#pragma unroll 4
    for (int hh = 0; hh < HID; ++hh) {
        bf16x8 bfv = *(const bf16x8*)(kwT + off);
        off += stride;
#pragma unroll
        for (int g = 0; g < EG; ++g) {
            f32x4 w  = __builtin_amdgcn_mfma_f32_16x16x32_bf16(af[g], bfv, z4,
                                                               0, 0, 0);
            f32x4 wr = __builtin_elementwise_max(w, z4);
            f32x4 hv = *(const f32x4*)&s_hT[hh][g * 16 + grp * 4];
            msg[g] += wr * hv;                 // contracts to v_pk_fma_f32
        }
    }

    // scatter
#pragma unroll
    for (int g = 0; g < EG; ++g) {
#pragma unroll
        for (int j = 0; j < 4; ++j) {
            int dst = s_dst[g * 16 + grp * 4 + j];
            atomicAdd(num + (size_t)dst * HID + q * 16 + col, msg[g][j]);
        }
    }
    if (tid < EG * 16) atomicAdd(cnt + s_dst[tid], 1.f);
}

// ---------------------------------------------------------------------------
// Kernel C (MFMA): agg/root/heads fused. Block = 16 nodes.
// ---------------------------------------------------------------------------
__global__ __launch_bounds__(256) void k_out(
        const float* __restrict__ h, const float* __restrict__ num,
        const float* __restrict__ cnt,
        const __hip_bfloat16* __restrict__ rootT, const float* __restrict__ conv_b,
        const __hip_bfloat16* __restrict__ mlvT,  const float* __restrict__ mu_b,
        const float* __restrict__ lv_b, float* __restrict__ out) {
    __shared__ __align__(16) __hip_bfloat16 s_h2[16][72];
    const int n0   = blockIdx.x * 16;
    const int q    = threadIdx.x >> 6;
    const int lane = threadIdx.x & 63;
    const int col  = lane & 15, grp = lane >> 4;
    const int oo   = q * 16 + col;

    f32x4 acc = {0.f, 0.f, 0.f, 0.f};
    const float* hp = h + (size_t)(n0 + col) * HID + grp * 8;
    const __hip_bfloat16* bp = rootT + (size_t)oo * HID + grp * 8;
#pragma unroll
    for (int it = 0; it < 2; ++it) {
        float4 xa = *(const float4*)(hp + it * 32);
        float4 xb = *(const float4*)(hp + it * 32 + 4);
        bf16x8 af;
        af[0] = f2bs(xa.x); af[1] = f2bs(xa.y); af[2] = f2bs(xa.z); af[3] = f2bs(xa.w);
        af[4] = f2bs(xb.x); af[5] = f2bs(xb.y); af[6] = f2bs(xb.z); af[7] = f2bs(xb.w);
        bf16x8 bfv = *(const bf16x8*)(bp + it * 32);
        acc = __builtin_amdgcn_mfma_f32_16x16x32_bf16(af, bfv, acc, 0, 0, 0);
    }
    const float cb = conv_b[oo];
#pragma unroll
    for (int j = 0; j < 4; ++j) {
        int row = grp * 4 + j;
        int n = n0 + row;
        float agg = num[(size_t)n * HID + oo] / fmaxf(cnt[n], 1.f);
        s_h2[row][oo] = __float2bfloat16(fmaxf(acc[j] + agg + cb, 0.f));
    }
    __syncthreads();

    f32x4 acc2 = {0.f, 0.f, 0.f, 0.f};
    const __hip_bfloat16* b2 = mlvT + (size_t)oo * HID + grp * 8;
#pragma unroll
    for (int it = 0; it < 2; ++it) {
        bf16x8 af = *(const bf16x8*)((const char*)&s_h2[col][0] + it * 64 + grp * 16);
        bf16x8 bfv = *(const bf16x8*)(b2 + it * 32);
        acc2 = __builtin_amdgcn_mfma_f32_16x16x32_bf16(af, bfv, acc2, 0, 0, 0);
    }
    const float bias = (oo < 32) ? mu_b[oo] : lv_b[oo - 32];
    float* obase = (oo < 32) ? (out + oo) : (out + (size_t)N_NODES * LAT + (oo - 32));
#pragma unroll
    for (int j = 0; j < 4; ++j) {
        int n = n0 + grp * 4 + j;
        obase[(size_t)n * LAT] = acc2[j] + bias;
    }
}

// ---------------------------------------------------------------------------
extern "C" void kernel_launch(void* const* d_in, const int* in_sizes, int n_in,
                              void* d_out, int out_size, void* d_ws, size_t ws_size,
                              hipStream_t stream) {
    const float* x      = (const float*)d_in[0];
    const int*   ei     = (const int*)  d_in[1];
    const float* ea     = (const float*)d_in[2];
    const float* lin_w  = (const float*)d_in[3];
    const float* lin_b  = (const float*)d_in[4];
    const float* kw     = (const float*)d_in[5];
    const float* kb     = (const float*)d_in[6];
    const float* root_w = (const float*)d_in[7];
    const float* conv_b = (const float*)d_in[8];
    const float* mu_w   = (const float*)d_in[9];
    const float* mu_b   = (const float*)d_in[10];
    const float* lv_w   = (const float*)d_in[11];
    const float* lv_b   = (const float*)d_in[12];
    float* out = (float*)d_out;

    float* h   = (float*)d_ws;
    float* num = h   + (size_t)N_NODES * HID;
    float* cnt = num + (size_t)N_NODES * HID;
    __hip_bfloat16* kwT   = (__hip_bfloat16*)(cnt + N_NODES);  // 65536
    __hip_bfloat16* kbb8  = kwT   + 65536;                     // 32768
    __hip_bfloat16* wT    = kbb8  + 32768;                     // 8192
    __hip_bfloat16* rootT = wT    + 8192;                      // 4096
    __hip_bfloat16* mlvT  = rootT + 4096;                      // 4096

    hipMemsetAsync(num, 0, (size_t)(N_NODES * HID + N_NODES) * sizeof(float),
                   stream);

    k_prep<<<448, 256, 0, stream>>>(kw, kb, lin_w, root_w, mu_w, lv_w,
                                    kwT, kbb8, wT, rootT, mlvT);

    k_lin_mfma<<<N_NODES / 16, 256, 0, stream>>>(x, wT, lin_b, h);

    k_edge<<<N_EDGES / (EG * 16), 256, 0, stream>>>(ei, ea, h, kwT, num, cnt);

    k_out<<<N_NODES / 16, 256, 0, stream>>>(h, num, cnt, rootT, conv_b,
                                            mlvT, mu_b, lv_b, out);
}

// Round 7
// 106.804 us; speedup vs baseline: 1.0167x; 1.0167x over previous
//
#include <hip/hip_runtime.h>
#include <hip/hip_bf16.h>

#define N_NODES 20000
#define N_EDGES 100000
#define IN_DIM  128
#define HID     64
#define LAT     32
#define EDIM    16

typedef __attribute__((ext_vector_type(8))) short bf16x8;
typedef __attribute__((ext_vector_type(4))) float f32x4;

__device__ __forceinline__ short f2bs(float f) {
    __hip_bfloat16 b = __float2bfloat16(f);
    short s;
    __builtin_memcpy(&s, &b, 2);
    return s;
}

// packed bf16 atomic add: mem[p] += lo, mem[p+1] += hi (device scope)
__device__ __forceinline__ void atom_pk_bf16(__hip_bfloat16* p, float a, float b) {
    union { struct { short lo, hi; } s; unsigned int u; } v;
    v.s.lo = f2bs(a);
    v.s.hi = f2bs(b);
    asm volatile("global_atomic_pk_add_bf16 %0, %1, off"
                 :: "v"((unsigned long long)(uintptr_t)p), "v"(v.u) : "memory");
}

// ---------------------------------------------------------------------------
// Fused prep: build all bf16 transposed weight tables in ws.
//   kwT  [4096][16] : kwT[c][d]  = kw[d][c]          (65536)
//   kbb8 [4096][8]  : kb[c] replicated 8x            (32768)   (kwT+65536)
//   wT   [64][128]  : wT[o][d]   = lin_w[d][o]       (8192)
//   rootT[64][64]   : rootT[o][d]= root_w[d][o]      (4096)
//   mlvT [64][64]   : o<32 -> mu_w[k][o], else lv_w  (4096)
// ---------------------------------------------------------------------------
__global__ __launch_bounds__(256) void k_prep(
        const float* __restrict__ kw,     const float* __restrict__ kb,
        const float* __restrict__ lin_w,  const float* __restrict__ root_w,
        const float* __restrict__ mu_w,   const float* __restrict__ lv_w,
        __hip_bfloat16* __restrict__ kwT, __hip_bfloat16* __restrict__ kbb8,
        __hip_bfloat16* __restrict__ wT,  __hip_bfloat16* __restrict__ rootT,
        __hip_bfloat16* __restrict__ mlvT) {
    int i = blockIdx.x * 256 + threadIdx.x;
    if (i < 65536) {
        int c = i & 4095, d = i >> 12;
        kwT[c * EDIM + d] = __float2bfloat16(kw[d * (HID * HID) + c]);
    } else if (i < 65536 + 32768) {
        int j = i - 65536;
        kbb8[j] = __float2bfloat16(kb[j >> 3]);
    } else if (i < 65536 + 32768 + 8192) {
        int j = i - (65536 + 32768);
        int o = j >> 7, d = j & 127;
        wT[j] = __float2bfloat16(lin_w[d * HID + o]);
    } else if (i < 65536 + 32768 + 8192 + 4096) {
        int j = i - (65536 + 32768 + 8192);
        int o = j >> 6, d = j & 63;
        rootT[j] = __float2bfloat16(root_w[d * HID + o]);
    } else {
        int j = i - (65536 + 32768 + 8192 + 4096);
        int o2 = j >> 6, k = j & 63;
        mlvT[j] = __float2bfloat16(o2 < 32 ? mu_w[k * LAT + o2]
                                           : lv_w[k * LAT + (o2 - 32)]);
    }
}

// ---------------------------------------------------------------------------
// Kernel A (MFMA): h = relu(x @ lin_in_w + lin_in_b)
// ---------------------------------------------------------------------------
__global__ __launch_bounds__(256) void k_lin_mfma(
        const float* __restrict__ x, const __hip_bfloat16* __restrict__ wT,
        const float* __restrict__ lin_b, float* __restrict__ h) {
    const int n0   = blockIdx.x * 16;
    const int q    = threadIdx.x >> 6;
    const int lane = threadIdx.x & 63;
    const int col  = lane & 15, grp = lane >> 4;
    const int oo   = q * 16 + col;

    f32x4 acc = {0.f, 0.f, 0.f, 0.f};
    const float* xp = x + (size_t)(n0 + col) * IN_DIM + grp * 8;
    const __hip_bfloat16* bp = wT + (size_t)oo * IN_DIM + grp * 8;
#pragma unroll
    for (int it = 0; it < 4; ++it) {
        float4 xa = *(const float4*)(xp + it * 32);
        float4 xb = *(const float4*)(xp + it * 32 + 4);
        bf16x8 af;
        af[0] = f2bs(xa.x); af[1] = f2bs(xa.y); af[2] = f2bs(xa.z); af[3] = f2bs(xa.w);
        af[4] = f2bs(xb.x); af[5] = f2bs(xb.y); af[6] = f2bs(xb.z); af[7] = f2bs(xb.w);
        bf16x8 bfv = *(const bf16x8*)(bp + it * 32);
        acc = __builtin_amdgcn_mfma_f32_16x16x32_bf16(af, bfv, acc, 0, 0, 0);
    }
    const float bias = lin_b[oo];
#pragma unroll
    for (int j = 0; j < 4; ++j) {
        int row = grp * 4 + j;
        h[(size_t)(n0 + row) * HID + oo] = fmaxf(acc[j] + bias, 0.f);
    }
}

// ---------------------------------------------------------------------------
// Kernel B (MFMA, transposed mapping): fused edge-MLP + message + scatter.
// Block = 16 edges, wave q = oo quarter. Per hh one 16x16x32 MFMA computes
// the TRANSPOSED tile D[oo, edge]:
//   A (stream) : row = oo (lane&15), k<16 = kwT row d-halves (grp0/1),
//                k=16..23 = kbb8 bias row (grp2), k>=24 = don't-care (grp3)
//   B (fixed)  : col = edge (lane&15), k<16 = edge_attr, k=16 -> 1.0 (grp2)
// D: col = lane&15 = edge, row = grp*4+j = oo. Epilogue: msg[j] +=
// relu(w[j]) * hv where hv = s_h[edge][hh] is ONE scalar per lane, read as
// ds_read_b128 once per 4 hh. Scatter: packed bf16 atomics (2 oo per op).
// ---------------------------------------------------------------------------
__global__ __launch_bounds__(256) void k_edge(
        const int* __restrict__ ei, const float* __restrict__ ea,
        const float* __restrict__ h, const __hip_bfloat16* __restrict__ kwT,
        __hip_bfloat16* __restrict__ num, float* __restrict__ cnt) {
    __shared__ float s_h[16][68];     // row-major h_src, pad to 68 floats
    __shared__ int   s_dst[16];

    const int e0   = blockIdx.x * 16;
    const int tid  = threadIdx.x;
    const int q    = tid >> 6, lane = tid & 63;
    const int col  = lane & 15, grp = lane >> 4;

    // stage h[src] row-major (no transpose): fully coalesced, conflict-free
    for (int i = tid; i < 16 * HID; i += 256) {
        int r = i >> 6, c = i & 63;
        int src = ei[e0 + r];
        s_h[r][c] = h[(size_t)src * HID + c];
    }
    if (tid < 16) s_dst[tid] = ei[N_EDGES + e0 + tid];
    __syncthreads();

    // B fragment (fixed): edge_attr of edge (e0+col); bias 1.0 at k=16
    bf16x8 bfrag = {};
    if (grp < 2) {
        const float* ep = ea + (size_t)(e0 + col) * EDIM + grp * 8;
        float4 a0 = *(const float4*)ep;
        float4 a1 = *(const float4*)(ep + 4);
        bfrag[0] = f2bs(a0.x); bfrag[1] = f2bs(a0.y);
        bfrag[2] = f2bs(a0.z); bfrag[3] = f2bs(a0.w);
        bfrag[4] = f2bs(a1.x); bfrag[5] = f2bs(a1.y);
        bfrag[6] = f2bs(a1.z); bfrag[7] = f2bs(a1.w);
    } else if (grp == 2) {
        bfrag[0] = (short)0x3F80;     // bf16(1.0) at k=16 -> bias slot
    }

    // A-stream offset (elements into kwT||kbb8), per-lane constant stride
    int off, stride;
    if (grp < 2) { off = (q * 16 + col) * EDIM + grp * 8; stride = 1024; }
    else         { off = 65536 + (q * 16 + col) * 8;      stride = 512;  }

    f32x4 msg = {0.f, 0.f, 0.f, 0.f};
    const f32x4 z4 = {0.f, 0.f, 0.f, 0.f};

#pragma unroll 2
    for (int hc = 0; hc < 16; ++hc) {           // 4 hh per chunk
        float4 hv = *(const float4*)&s_h[col][hc * 4];
#pragma unroll
        for (int u = 0; u < 4; ++u) {
            bf16x8 afr = *(const bf16x8*)(kwT + off);
            off += stride;
            f32x4 w = __builtin_amdgcn_mfma_f32_16x16x32_bf16(afr, bfrag, z4,
                                                              0, 0, 0);
            const float hvu = (u == 0) ? hv.x : (u == 1) ? hv.y
                            : (u == 2) ? hv.z : hv.w;
            msg[0] = fmaf(fmaxf(w[0], 0.f), hvu, msg[0]);
            msg[1] = fmaf(fmaxf(w[1], 0.f), hvu, msg[1]);
            msg[2] = fmaf(fmaxf(w[2], 0.f), hvu, msg[2]);
            msg[3] = fmaf(fmaxf(w[3], 0.f), hvu, msg[3]);
        }
    }

    // scatter: lane owns edge=col, oo = q*16 + grp*4 + {0..3} (contiguous)
    {
        int dst = s_dst[col];
        __hip_bfloat16* base = num + (size_t)dst * HID + q * 16 + grp * 4;
        atom_pk_bf16(base,     msg[0], msg[1]);
        atom_pk_bf16(base + 2, msg[2], msg[3]);
    }
    if (tid < 16) atomicAdd(cnt + s_dst[tid], 1.f);
}

// ---------------------------------------------------------------------------
// Kernel C (MFMA): agg/root/heads fused. Block = 16 nodes.
// ---------------------------------------------------------------------------
__global__ __launch_bounds__(256) void k_out(
        const float* __restrict__ h, const __hip_bfloat16* __restrict__ numb,
        const float* __restrict__ cnt,
        const __hip_bfloat16* __restrict__ rootT, const float* __restrict__ conv_b,
        const __hip_bfloat16* __restrict__ mlvT,  const float* __restrict__ mu_b,
        const float* __restrict__ lv_b, float* __restrict__ out) {
    __shared__ __align__(16) __hip_bfloat16 s_h2[16][72];
    const int n0   = blockIdx.x * 16;
    const int q    = threadIdx.x >> 6;
    const int lane = threadIdx.x & 63;
    const int col  = lane & 15, grp = lane >> 4;
    const int oo   = q * 16 + col;

    f32x4 acc = {0.f, 0.f, 0.f, 0.f};
    const float* hp = h + (size_t)(n0 + col) * HID + grp * 8;
    const __hip_bfloat16* bp = rootT + (size_t)oo * HID + grp * 8;
#pragma unroll
    for (int it = 0; it < 2; ++it) {
        float4 xa = *(const float4*)(hp + it * 32);
        float4 xb = *(const float4*)(hp + it * 32 + 4);
        bf16x8 af;
        af[0] = f2bs(xa.x); af[1] = f2bs(xa.y); af[2] = f2bs(xa.z); af[3] = f2bs(xa.w);
        af[4] = f2bs(xb.x); af[5] = f2bs(xb.y); af[6] = f2bs(xb.z); af[7] = f2bs(xb.w);
        bf16x8 bfv = *(const bf16x8*)(bp + it * 32);
        acc = __builtin_amdgcn_mfma_f32_16x16x32_bf16(af, bfv, acc, 0, 0, 0);
    }
    const float cb = conv_b[oo];
#pragma unroll
    for (int j = 0; j < 4; ++j) {
        int row = grp * 4 + j;
        int n = n0 + row;
        float agg = __bfloat162float(numb[(size_t)n * HID + oo])
                    / fmaxf(cnt[n], 1.f);
        s_h2[row][oo] = __float2bfloat16(fmaxf(acc[j] + agg + cb, 0.f));
    }
    __syncthreads();

    f32x4 acc2 = {0.f, 0.f, 0.f, 0.f};
    const __hip_bfloat16* b2 = mlvT + (size_t)oo * HID + grp * 8;
#pragma unroll
    for (int it = 0; it < 2; ++it) {
        bf16x8 af = *(const bf16x8*)((const char*)&s_h2[col][0] + it * 64 + grp * 16);
        bf16x8 bfv = *(const bf16x8*)(b2 + it * 32);
        acc2 = __builtin_amdgcn_mfma_f32_16x16x32_bf16(af, bfv, acc2, 0, 0, 0);
    }
    const float bias = (oo < 32) ? mu_b[oo] : lv_b[oo - 32];
    float* obase = (oo < 32) ? (out + oo) : (out + (size_t)N_NODES * LAT + (oo - 32));
#pragma unroll
    for (int j = 0; j < 4; ++j) {
        int n = n0 + grp * 4 + j;
        obase[(size_t)n * LAT] = acc2[j] + bias;
    }
}

// ---------------------------------------------------------------------------
extern "C" void kernel_launch(void* const* d_in, const int* in_sizes, int n_in,
                              void* d_out, int out_size, void* d_ws, size_t ws_size,
                              hipStream_t stream) {
    const float* x      = (const float*)d_in[0];
    const int*   ei     = (const int*)  d_in[1];
    const float* ea     = (const float*)d_in[2];
    const float* lin_w  = (const float*)d_in[3];
    const float* lin_b  = (const float*)d_in[4];
    const float* kw     = (const float*)d_in[5];
    const float* kb     = (const float*)d_in[6];
    const float* root_w = (const float*)d_in[7];
    const float* conv_b = (const float*)d_in[8];
    const float* mu_w   = (const float*)d_in[9];
    const float* mu_b   = (const float*)d_in[10];
    const float* lv_w   = (const float*)d_in[11];
    const float* lv_b   = (const float*)d_in[12];
    float* out = (float*)d_out;

    float* h   = (float*)d_ws;                               // N*64 f32
    float* cnt = h + (size_t)N_NODES * HID;                  // N f32
    __hip_bfloat16* numb  = (__hip_bfloat16*)(cnt + N_NODES);   // N*64 bf16
    __hip_bfloat16* kwT   = numb  + (size_t)N_NODES * HID;      // 65536
    __hip_bfloat16* kbb8  = kwT   + 65536;                      // 32768
    __hip_bfloat16* wT    = kbb8  + 32768;                      // 8192
    __hip_bfloat16* rootT = wT    + 8192;                       // 4096
    __hip_bfloat16* mlvT  = rootT + 4096;                       // 4096

    // zero cnt (f32) + numb (bf16) in one contiguous memset
    hipMemsetAsync(cnt, 0,
                   (size_t)N_NODES * sizeof(float) +
                   (size_t)N_NODES * HID * sizeof(__hip_bfloat16), stream);

    k_prep<<<448, 256, 0, stream>>>(kw, kb, lin_w, root_w, mu_w, lv_w,
                                    kwT, kbb8, wT, rootT, mlvT);

    k_lin_mfma<<<N_NODES / 16, 256, 0, stream>>>(x, wT, lin_b, h);

    k_edge<<<N_EDGES / 16, 256, 0, stream>>>(ei, ea, h, kwT, numb, cnt);

    k_out<<<N_NODES / 16, 256, 0, stream>>>(h, numb, cnt, rootT, conv_b,
                                            mlvT, mu_b, lv_b, out);
}

// Round 8
// 106.208 us; speedup vs baseline: 1.0224x; 1.0056x over previous
//
#include <hip/hip_runtime.h>
#include <hip/hip_bf16.h>

#define N_NODES 20000
#define N_EDGES 100000
#define IN_DIM  128
#define HID     64
#define LAT     32
#define EDIM    16
#define CH      8      // hh per staged chunk in k_edge

typedef __attribute__((ext_vector_type(8))) short bf16x8;
typedef __attribute__((ext_vector_type(4))) float f32x4;
typedef __attribute__((ext_vector_type(4))) int   i32x4;

__device__ __forceinline__ short f2bs(float f) {
    __hip_bfloat16 b = __float2bfloat16(f);
    short s;
    __builtin_memcpy(&s, &b, 2);
    return s;
}

// packed bf16 atomic add: mem[p] += lo, mem[p+1] += hi (device scope)
__device__ __forceinline__ void atom_pk_bf16(__hip_bfloat16* p, float a, float b) {
    union { struct { short lo, hi; } s; unsigned int u; } v;
    v.s.lo = f2bs(a);
    v.s.hi = f2bs(b);
    asm volatile("global_atomic_pk_add_bf16 %0, %1, off"
                 :: "v"((unsigned long long)(uintptr_t)p), "v"(v.u) : "memory");
}

// ---------------------------------------------------------------------------
// Fused prep:
//   kwA  [64][64][24] shorts: per (hh,oo): [kw[d][hh*64+oo] d=0..15 | kb x8]
//        -> MFMA-ready A rows (k<16 = weights, k=16..23 = bias replicated);
//           layout identical in global and LDS (row = 48 B, 16B-aligned).
//   wT   [64][128]  : wT[o][d]   = lin_w[d][o]       (8192)
//   rootT[64][64]   : rootT[o][d]= root_w[d][o]      (4096)
//   mlvT [64][64]   : o<32 -> mu_w[k][o], else lv_w  (4096)
// total = 98304 + 8192 + 4096 + 4096 = 114688 = 448 * 256
// ---------------------------------------------------------------------------
__global__ __launch_bounds__(256) void k_prep(
        const float* __restrict__ kw,     const float* __restrict__ kb,
        const float* __restrict__ lin_w,  const float* __restrict__ root_w,
        const float* __restrict__ mu_w,   const float* __restrict__ lv_w,
        short* __restrict__ kwA,          __hip_bfloat16* __restrict__ wT,
        __hip_bfloat16* __restrict__ rootT, __hip_bfloat16* __restrict__ mlvT) {
    int i = blockIdx.x * 256 + threadIdx.x;
    if (i < 98304) {
        int hh  = i / 1536;
        int rem = i - hh * 1536;
        int oo  = rem / 24;
        int s   = rem - oo * 24;
        int c   = hh * 64 + oo;
        float v = (s < 16) ? kw[s * (HID * HID) + c] : kb[c];
        kwA[i] = f2bs(v);
    } else if (i < 98304 + 8192) {
        int j = i - 98304;
        int o = j >> 7, d = j & 127;
        wT[j] = __float2bfloat16(lin_w[d * HID + o]);
    } else if (i < 98304 + 8192 + 4096) {
        int j = i - (98304 + 8192);
        int o = j >> 6, d = j & 63;
        rootT[j] = __float2bfloat16(root_w[d * HID + o]);
    } else {
        int j = i - (98304 + 8192 + 4096);
        int o2 = j >> 6, k = j & 63;
        mlvT[j] = __float2bfloat16(o2 < 32 ? mu_w[k * LAT + o2]
                                           : lv_w[k * LAT + (o2 - 32)]);
    }
}

// ---------------------------------------------------------------------------
// Kernel A (MFMA): h = relu(x @ lin_in_w + lin_in_b)
// ---------------------------------------------------------------------------
__global__ __launch_bounds__(256) void k_lin_mfma(
        const float* __restrict__ x, const __hip_bfloat16* __restrict__ wT,
        const float* __restrict__ lin_b, float* __restrict__ h) {
    const int n0   = blockIdx.x * 16;
    const int q    = threadIdx.x >> 6;
    const int lane = threadIdx.x & 63;
    const int col  = lane & 15, grp = lane >> 4;
    const int oo   = q * 16 + col;

    f32x4 acc = {0.f, 0.f, 0.f, 0.f};
    const float* xp = x + (size_t)(n0 + col) * IN_DIM + grp * 8;
    const __hip_bfloat16* bp = wT + (size_t)oo * IN_DIM + grp * 8;
#pragma unroll
    for (int it = 0; it < 4; ++it) {
        float4 xa = *(const float4*)(xp + it * 32);
        float4 xb = *(const float4*)(xp + it * 32 + 4);
        bf16x8 af;
        af[0] = f2bs(xa.x); af[1] = f2bs(xa.y); af[2] = f2bs(xa.z); af[3] = f2bs(xa.w);
        af[4] = f2bs(xb.x); af[5] = f2bs(xb.y); af[6] = f2bs(xb.z); af[7] = f2bs(xb.w);
        bf16x8 bfv = *(const bf16x8*)(bp + it * 32);
        acc = __builtin_amdgcn_mfma_f32_16x16x32_bf16(af, bfv, acc, 0, 0, 0);
    }
    const float bias = lin_b[oo];
#pragma unroll
    for (int j = 0; j < 4; ++j) {
        int row = grp * 4 + j;
        h[(size_t)(n0 + row) * HID + oo] = fmaxf(acc[j] + bias, 0.f);
    }
}

// ---------------------------------------------------------------------------
// Kernel B (MFMA, LDS-staged weights): fused edge-MLP + message + scatter.
// 512 threads / 8 waves / 64 edges per block. Wave = (q = oo quarter,
// egp = edge-pair); per hh: ONE ds_read_b128 of the staged A row
// (kwA: k<16 weights, k=16 bias), TWO MFMAs (edge-groups) reusing it.
//   A row = oo (lane&15 within quarter q), B col = edge, B k=16 -> 1.0.
//   D: row = grp*4+j = oo, col = edge. Epilogue: msg += relu(w) * h_scalar.
// kwA chunk (8 hh = 24 KB) staged global->LDS per chunk, identical layout,
// with next-chunk prefetch issued before compute (latency hidden).
// Scatter: packed bf16 atomics. Tail (last block: 32 valid edges) clamped.
// ---------------------------------------------------------------------------
__global__ __launch_bounds__(512) void k_edge(
        const int* __restrict__ ei, const float* __restrict__ ea,
        const float* __restrict__ h, const short* __restrict__ kwA,
        __hip_bfloat16* __restrict__ num, float* __restrict__ cnt) {
    __shared__ __align__(16) short s_a[CH * 64 * 24];   // 24576 B
    __shared__ __align__(16) float s_h[64][68];         // 17408 B
    __shared__ int s_dst[64];

    const int e0   = blockIdx.x * 64;
    const int tid  = threadIdx.x;
    const int w    = tid >> 6;
    const int lane = tid & 63;
    const int q    = w & 3, egp = w >> 2;
    const int col  = lane & 15, grp = lane >> 4;

    // stage h[src] (64 edges x 64 hh), row-major, coalesced
    for (int i = tid; i < 64 * HID; i += 512) {
        int r = i >> 6, c = i & 63;
        int e = e0 + r; if (e >= N_EDGES) e = N_EDGES - 1;
        int src = ei[e];
        s_h[r][c] = h[(size_t)src * HID + c];
    }
    if (tid < 64) {
        int e = e0 + tid; if (e >= N_EDGES) e = N_EDGES - 1;
        s_dst[tid] = ei[N_EDGES + e];
    }

    // B fragments (fixed): edge_attr of this wave's two 16-edge groups
    bf16x8 bfrag[2];
#pragma unroll
    for (int g = 0; g < 2; ++g) {
        bf16x8 b = {};
        if (grp < 2) {
            int e = e0 + (egp * 2 + g) * 16 + col;
            if (e >= N_EDGES) e = N_EDGES - 1;
            const float* ep = ea + (size_t)e * EDIM + grp * 8;
            float4 a0 = *(const float4*)ep;
            float4 a1 = *(const float4*)(ep + 4);
            b[0] = f2bs(a0.x); b[1] = f2bs(a0.y); b[2] = f2bs(a0.z); b[3] = f2bs(a0.w);
            b[4] = f2bs(a1.x); b[5] = f2bs(a1.y); b[6] = f2bs(a1.z); b[7] = f2bs(a1.w);
        } else if (grp == 2) {
            b[0] = (short)0x3F80;     // bf16(1.0) at k=16 -> bias slot
        }
        bfrag[g] = b;
    }

    // per-lane A read base within a chunk (shorts): row stride 24 (48 B)
    const int asel  = (grp < 2) ? grp : 2;
    const int abase = (q * 16 + col) * 24 + asel * 8;

    f32x4 msg[2] = {{0.f,0.f,0.f,0.f},{0.f,0.f,0.f,0.f}};
    const f32x4 z4 = {0.f, 0.f, 0.f, 0.f};

    // prefetch chunk 0 into registers
    i32x4 st[3];
#pragma unroll
    for (int p = 0; p < 3; ++p)
        st[p] = *(const i32x4*)(kwA + (tid + p * 512) * 8);

#pragma unroll 1
    for (int ch = 0; ch < HID / CH; ++ch) {
        __syncthreads();              // prior chunk's LDS reads complete
#pragma unroll
        for (int p = 0; p < 3; ++p)
            *(i32x4*)(s_a + (tid + p * 512) * 8) = st[p];
        if (ch + 1 < HID / CH) {      // issue next chunk's loads early (T14)
            const short* gsrc = kwA + (ch + 1) * (CH * 64 * 24);
#pragma unroll
            for (int p = 0; p < 3; ++p)
                st[p] = *(const i32x4*)(gsrc + (tid + p * 512) * 8);
        }
        __syncthreads();              // staged chunk visible

        int aoff = abase;
#pragma unroll
        for (int hl4 = 0; hl4 < 2; ++hl4) {
            float4 hv0 = *(const float4*)&s_h[(egp * 2 + 0) * 16 + col][ch * CH + hl4 * 4];
            float4 hv1 = *(const float4*)&s_h[(egp * 2 + 1) * 16 + col][ch * CH + hl4 * 4];
#pragma unroll
            for (int u = 0; u < 4; ++u) {
                bf16x8 afr = *(const bf16x8*)(s_a + aoff);
                aoff += 1536;         // next hh within chunk (64*24 shorts)
                f32x4 w0 = __builtin_amdgcn_mfma_f32_16x16x32_bf16(afr, bfrag[0], z4, 0, 0, 0);
                f32x4 w1 = __builtin_amdgcn_mfma_f32_16x16x32_bf16(afr, bfrag[1], z4, 0, 0, 0);
                const float h0 = (u == 0) ? hv0.x : (u == 1) ? hv0.y : (u == 2) ? hv0.z : hv0.w;
                const float h1 = (u == 0) ? hv1.x : (u == 1) ? hv1.y : (u == 2) ? hv1.z : hv1.w;
                msg[0][0] = fmaf(fmaxf(w0[0], 0.f), h0, msg[0][0]);
                msg[0][1] = fmaf(fmaxf(w0[1], 0.f), h0, msg[0][1]);
                msg[0][2] = fmaf(fmaxf(w0[2], 0.f), h0, msg[0][2]);
                msg[0][3] = fmaf(fmaxf(w0[3], 0.f), h0, msg[0][3]);
                msg[1][0] = fmaf(fmaxf(w1[0], 0.f), h1, msg[1][0]);
                msg[1][1] = fmaf(fmaxf(w1[1], 0.f), h1, msg[1][1]);
                msg[1][2] = fmaf(fmaxf(w1[2], 0.f), h1, msg[1][2]);
                msg[1][3] = fmaf(fmaxf(w1[3], 0.f), h1, msg[1][3]);
            }
        }
    }

    // scatter: lane owns edge = group*16+col, oo = q*16 + grp*4 + {0..3}
#pragma unroll
    for (int g = 0; g < 2; ++g) {
        int el = (egp * 2 + g) * 16 + col;
        if (e0 + el < N_EDGES) {
            int dst = s_dst[el];
            __hip_bfloat16* base = num + (size_t)dst * HID + q * 16 + grp * 4;
            atom_pk_bf16(base,     msg[g][0], msg[g][1]);
            atom_pk_bf16(base + 2, msg[g][2], msg[g][3]);
        }
    }
    if (tid < 64 && e0 + tid < N_EDGES)
        atomicAdd(cnt + s_dst[tid], 1.f);
}

// ---------------------------------------------------------------------------
// Kernel C (MFMA): agg/root/heads fused. Block = 16 nodes.
// ---------------------------------------------------------------------------
__global__ __launch_bounds__(256) void k_out(
        const float* __restrict__ h, const __hip_bfloat16* __restrict__ numb,
        const float* __restrict__ cnt,
        const __hip_bfloat16* __restrict__ rootT, const float* __restrict__ conv_b,
        const __hip_bfloat16* __restrict__ mlvT,  const float* __restrict__ mu_b,
        const float* __restrict__ lv_b, float* __restrict__ out) {
    __shared__ __align__(16) __hip_bfloat16 s_h2[16][72];
    const int n0   = blockIdx.x * 16;
    const int q    = threadIdx.x >> 6;
    const int lane = threadIdx.x & 63;
    const int col  = lane & 15, grp = lane >> 4;
    const int oo   = q * 16 + col;

    f32x4 acc = {0.f, 0.f, 0.f, 0.f};
    const float* hp = h + (size_t)(n0 + col) * HID + grp * 8;
    const __hip_bfloat16* bp = rootT + (size_t)oo * HID + grp * 8;
#pragma unroll
    for (int it = 0; it < 2; ++it) {
        float4 xa = *(const float4*)(hp + it * 32);
        float4 xb = *(const float4*)(hp + it * 32 + 4);
        bf16x8 af;
        af[0] = f2bs(xa.x); af[1] = f2bs(xa.y); af[2] = f2bs(xa.z); af[3] = f2bs(xa.w);
        af[4] = f2bs(xb.x); af[5] = f2bs(xb.y); af[6] = f2bs(xb.z); af[7] = f2bs(xb.w);
        bf16x8 bfv = *(const bf16x8*)(bp + it * 32);
        acc = __builtin_amdgcn_mfma_f32_16x16x32_bf16(af, bfv, acc, 0, 0, 0);
    }
    const float cb = conv_b[oo];
#pragma unroll
    for (int j = 0; j < 4; ++j) {
        int row = grp * 4 + j;
        int n = n0 + row;
        float agg = __bfloat162float(numb[(size_t)n * HID + oo])
                    / fmaxf(cnt[n], 1.f);
        s_h2[row][oo] = __float2bfloat16(fmaxf(acc[j] + agg + cb, 0.f));
    }
    __syncthreads();

    f32x4 acc2 = {0.f, 0.f, 0.f, 0.f};
    const __hip_bfloat16* b2 = mlvT + (size_t)oo * HID + grp * 8;
#pragma unroll
    for (int it = 0; it < 2; ++it) {
        bf16x8 af = *(const bf16x8*)((const char*)&s_h2[col][0] + it * 64 + grp * 16);
        bf16x8 bfv = *(const bf16x8*)(b2 + it * 32);
        acc2 = __builtin_amdgcn_mfma_f32_16x16x32_bf16(af, bfv, acc2, 0, 0, 0);
    }
    const float bias = (oo < 32) ? mu_b[oo] : lv_b[oo - 32];
    float* obase = (oo < 32) ? (out + oo) : (out + (size_t)N_NODES * LAT + (oo - 32));
#pragma unroll
    for (int j = 0; j < 4; ++j) {
        int n = n0 + grp * 4 + j;
        obase[(size_t)n * LAT] = acc2[j] + bias;
    }
}

// ---------------------------------------------------------------------------
extern "C" void kernel_launch(void* const* d_in, const int* in_sizes, int n_in,
                              void* d_out, int out_size, void* d_ws, size_t ws_size,
                              hipStream_t stream) {
    const float* x      = (const float*)d_in[0];
    const int*   ei     = (const int*)  d_in[1];
    const float* ea     = (const float*)d_in[2];
    const float* lin_w  = (const float*)d_in[3];
    const float* lin_b  = (const float*)d_in[4];
    const float* kw     = (const float*)d_in[5];
    const float* kb     = (const float*)d_in[6];
    const float* root_w = (const float*)d_in[7];
    const float* conv_b = (const float*)d_in[8];
    const float* mu_w   = (const float*)d_in[9];
    const float* mu_b   = (const float*)d_in[10];
    const float* lv_w   = (const float*)d_in[11];
    const float* lv_b   = (const float*)d_in[12];
    float* out = (float*)d_out;

    float* h   = (float*)d_ws;                               // N*64 f32
    float* cnt = h + (size_t)N_NODES * HID;                  // N f32
    __hip_bfloat16* numb = (__hip_bfloat16*)(cnt + N_NODES); // N*64 bf16
    short* kwA = (short*)(numb + (size_t)N_NODES * HID);     // 98304 shorts
    __hip_bfloat16* wT    = (__hip_bfloat16*)(kwA + 98304);  // 8192
    __hip_bfloat16* rootT = wT + 8192;                       // 4096
    __hip_bfloat16* mlvT  = rootT + 4096;                    // 4096

    // zero cnt (f32) + numb (bf16) in one contiguous memset
    hipMemsetAsync(cnt, 0,
                   (size_t)N_NODES * sizeof(float) +
                   (size_t)N_NODES * HID * sizeof(__hip_bfloat16), stream);

    k_prep<<<448, 256, 0, stream>>>(kw, kb, lin_w, root_w, mu_w, lv_w,
                                    kwA, wT, rootT, mlvT);

    k_lin_mfma<<<N_NODES / 16, 256, 0, stream>>>(x, wT, lin_b, h);

    k_edge<<<(N_EDGES + 63) / 64, 512, 0, stream>>>(ei, ea, h, kwA, numb, cnt);

    k_out<<<N_NODES / 16, 256, 0, stream>>>(h, numb, cnt, rootT, conv_b,
                                            mlvT, mu_b, lv_b, out);
}